// Round 5
// baseline (587.225 us; speedup 1.0000x reference)
//
#include <hip/hip_runtime.h>
#include <hip/hip_bf16.h>
#include <stdint.h>

#define B_  4
#define S_  2048
#define D_  1024
#define H_  16
#define DK_ 64
#define M_  (B_*S_)                 // 8192
#define MD_ ((size_t)M_*D_)         // 8388608

typedef unsigned short u16;
typedef unsigned int   u32;
using bh8 = __attribute__((ext_vector_type(8))) short;
using fx4 = __attribute__((ext_vector_type(4))) float;
using us4 = __attribute__((ext_vector_type(4))) unsigned short;

#define C1_ 0.18033688011112042f    // (1/sqrt(64)) * log2(e)

__device__ __forceinline__ u16 f2bf(float f){
  union { float f; u32 u; } v; v.f = f;
  u32 r = v.u + 0x7FFFu + ((v.u >> 16) & 1u);
  return (u16)(r >> 16);
}
// truncating-ish bf16 (+half-ulp bias correction), 2 VALU ops
__device__ __forceinline__ u16 f2bf_fast(float f){
  union { float f; u32 u; } v; v.f = f;
  return (u16)((v.u + 0x8000u) >> 16);
}
// raw v_exp_f32 (2^x); s_nop covers the trans-use hazard
__device__ __forceinline__ float fexp2(float x){
  float r;
  asm("v_exp_f32 %0, %1\n\ts_nop 0" : "=v"(r) : "v"(x));
  return r;
}
// async global->LDS, 16B/lane; LDS dest must be wave-uniform base + lane*16
__device__ __forceinline__ void gl16(const void* g, void* l){
  __builtin_amdgcn_global_load_lds(
      (const __attribute__((address_space(1))) unsigned int*)g,
      (__attribute__((address_space(3))) unsigned int*)l, 16, 0, 0);
}

// ---------- 4x transpose+convert (z selects weight); z==0 (Wq) pre-scaled by C1_ ----------
__global__ __launch_bounds__(256) void transpose4_k(const float* __restrict__ W0,
                                                    const float* __restrict__ W1,
                                                    const float* __restrict__ W2,
                                                    const float* __restrict__ W3,
                                                    u16* __restrict__ out){
  int z = blockIdx.z;
  const float* in = (z==0)? W0 : (z==1)? W1 : (z==2)? W2 : W3;
  float scale = (z==0)? C1_ : 1.0f;
  u16* o = out + (size_t)z*1024*1024;
  __shared__ u16 tile[32][33];
  int tx = threadIdx.x, ty = threadIdx.y;
  int x0 = blockIdx.x*32, y0 = blockIdx.y*32;
  #pragma unroll
  for (int j=0;j<32;j+=8) tile[ty+j][tx] = f2bf(in[(size_t)(y0+ty+j)*D_ + x0+tx]*scale);
  __syncthreads();
  #pragma unroll
  for (int j=0;j<32;j+=8) o[(size_t)(x0+ty+j)*D_ + y0+tx] = tile[tx][ty+j];
}

// ---------- fp32 -> bf16 convert; z in {0,1} selects src, dst offset z*MD ----------
__global__ __launch_bounds__(256) void cvt_k(const float* __restrict__ s0,
                                             const float* __restrict__ s1,
                                             u16* __restrict__ dst, int n8){
  int z = blockIdx.z;
  const float* in = z ? s1 : s0;
  u16* out = dst + (size_t)z*MD_;
  int i = blockIdx.x*256 + threadIdx.x;
  if (i >= n8) return;
  const float4* p = (const float4*)(in + (size_t)i*8);
  float4 a0 = p[0], a1 = p[1];
  u16 o[8];
  o[0]=f2bf(a0.x); o[1]=f2bf(a0.y); o[2]=f2bf(a0.z); o[3]=f2bf(a0.w);
  o[4]=f2bf(a1.x); o[5]=f2bf(a1.y); o[6]=f2bf(a1.z); o[7]=f2bf(a1.w);
  *(bh8*)(out + (size_t)i*8) = *(bh8*)o;
}

// ---------- C = A @ BT^T, K=N=1024, bf16 in, fp32 accum ----------
// MODE 0: bf16 C (z-batched A/BT/C). MODE 1: fp32 C. MODE 2: bf16 C stored as
// per-head V^T: VtG[((b*16+h)*64+vd)*S + token].
// m97 structure: 128x128 tile, 4 waves, 4x4 mfma_f32_16x16x32_bf16,
// global_load_lds dwordx4 staging, slot = kc*128 + r.
template<int MODE>
__global__ __launch_bounds__(256) void gemm_bt(const u16* __restrict__ Abase,
                                               const u16* __restrict__ BTbase,
                                               void* __restrict__ Cbase){
  __shared__ __align__(16) u16 Asl[128*32];
  __shared__ __align__(16) u16 Bsl[128*32];
  int z = blockIdx.z;
  const u16* A  = Abase  + (size_t)z*MD_;
  const u16* BT = BTbase + (size_t)z*1024*1024;
  int tid  = threadIdx.x;
  int w    = tid >> 6, lane = tid & 63, quad = lane >> 4, ln = lane & 15;
  int waveM = w >> 1, waveN = w & 1;
  int rowBase = blockIdx.y*128, colBase = blockIdx.x*128;

  fx4 acc[4][4];
  #pragma unroll
  for (int i=0;i<4;i++)
    #pragma unroll
    for (int j=0;j<4;j++) acc[i][j] = (fx4){0.f,0.f,0.f,0.f};

  for (int k0 = 0; k0 < D_; k0 += 32){
    __syncthreads();
    #pragma unroll
    for (int i=0;i<2;i++){
      int slot = i*256 + tid;
      int kc = slot >> 7, r = slot & 127;
      gl16(&A [(size_t)(rowBase + r)*D_ + k0 + kc*8], &Asl[slot*8]);
      gl16(&BT[(size_t)(colBase + r)*D_ + k0 + kc*8], &Bsl[slot*8]);
    }
    __syncthreads();
    bh8 af[4], bf[4];
    #pragma unroll
    for (int t=0;t<4;t++){
      af[t] = *(const bh8*)(&Asl[(quad*128 + waveM*64 + t*16 + ln)*8]);
      bf[t] = *(const bh8*)(&Bsl[(quad*128 + waveN*64 + t*16 + ln)*8]);
    }
    #pragma unroll
    for (int i=0;i<4;i++)
      #pragma unroll
      for (int j=0;j<4;j++)
        acc[i][j] = __builtin_amdgcn_mfma_f32_16x16x32_bf16(af[i], bf[j], acc[i][j], 0, 0, 0);
  }

  // epilogue: C/D layout col = lane&15, row = quad*4 + reg  [m89/m91-verified]
  #pragma unroll
  for (int i=0;i<4;i++){
    int row0 = rowBase + waveM*64 + i*16 + quad*4;
    #pragma unroll
    for (int j=0;j<4;j++){
      int col = colBase + waveN*64 + j*16 + ln;
      if (MODE == 2){
        int bb = row0 >> 11, tok = row0 & (S_-1);
        int hh = col >> 6,  vd  = col & 63;
        us4 pk;
        #pragma unroll
        for (int r=0;r<4;r++) pk[r] = f2bf(acc[i][j][r]);
        *(us4*)&((u16*)Cbase)[((size_t)((bb*16+hh)*64+vd))*S_ + tok] = pk;
      } else {
        #pragma unroll
        for (int r=0;r<4;r++){
          if (MODE == 1) ((float*)Cbase)[(size_t)(row0 + r)*D_ + col] = acc[i][j][r];
          else ((u16*)Cbase + (size_t)z*MD_)[(size_t)(row0 + r)*D_ + col] = f2bf(acc[i][j][r]);
        }
      }
    }
  }
}

// ---------- flash attention, causal ----------
// Block = 128 q-rows (4 waves x 32 rows as 2 row-groups); k-tile = 128.
// Q pre-scaled by C1_ (folded into Wq) -> scores already in log2 domain.
// Mask applied only on the diagonal tile. Per-wave P buffer (16 rows) reused
// across the two row-groups (wave-local lgkm ordering). XOR-swizzled 16B chunk
// slots throughout (R4-verified, 0 bank conflicts). O aliases Q (disjoint per
// block; Q read into regs before first store).
__global__ __launch_bounds__(256) void attn_k(const u16* __restrict__ Q,
                                              const u16* __restrict__ Kp,
                                              const u16* __restrict__ VtG,
                                              u16* __restrict__ O){
  __shared__ __align__(16) u16 Kt[128*64];    // 16 KB: key n, dk-chunk kc
  __shared__ __align__(16) u16 Vt[64*128];    // 16 KB: vd, kpos-chunk c
  __shared__ __align__(16) u16 Pb[4*16*128];  // 16 KB: per-wave 16q x 128k

  int qt = (int)gridDim.x - 1 - (int)blockIdx.x;   // heavy blocks first
  int bh = blockIdx.y; int b = bh>>4, h = bh&15;
  int tid = threadIdx.x;
  int w = tid >> 6, lane = tid & 63, quad = lane >> 4, ln = lane & 15;
  int q0w = qt*128 + w*32;
  size_t headoff = (size_t)h*DK_;

  bh8 qf[2][2];
  #pragma unroll
  for (int rg=0; rg<2; rg++){
    const u16* qp = Q + (size_t)(b*S_ + q0w + rg*16 + ln)*D_ + headoff + quad*8;
    qf[rg][0] = *(const bh8*)qp;
    qf[rg][1] = *(const bh8*)(qp + 32);
  }

  float m_i[2][4], l_i[2][4];
  fx4 oacc[2][4];
  #pragma unroll
  for (int rg=0; rg<2; rg++)
    #pragma unroll
    for (int r=0;r<4;r++){
      m_i[rg][r] = -3e38f; l_i[rg][r] = 0.f;
      oacc[rg][r] = (fx4){0.f,0.f,0.f,0.f};
    }

  u16* Pw = &Pb[w*16*128];
  int ntiles = qt + 1;
  for (int kt=0; kt<ntiles; kt++){
    int k0 = kt*128;
    __syncthreads();
    // stage K: slot s -> (n = s>>3, kc = (s&7) ^ (n&7))
    #pragma unroll
    for (int i=0;i<4;i++){
      int s = i*256 + tid;
      int n = s >> 3, kc = (s & 7) ^ (n & 7);
      gl16(&Kp[(size_t)(b*S_ + k0 + n)*D_ + headoff + kc*8], &Kt[s*8]);
    }
    // stage V^T: slot s -> (vd = s>>4, c = (s&15) ^ (vd&15))
    #pragma unroll
    for (int i=0;i<4;i++){
      int s = i*256 + tid;
      int vd = s >> 4, c = (s & 15) ^ (vd & 15);
      gl16(&VtG[(size_t)(bh*64 + vd)*S_ + k0 + c*8], &Vt[s*8]);
    }
    __syncthreads();

    bool diag = (kt == qt);
    #pragma unroll
    for (int rg=0; rg<2; rg++){
      // QK^T: 16q x 128k = 8 accs, 2 dk-steps
      fx4 sacc[8];
      #pragma unroll
      for (int t=0;t<8;t++){
        int n = t*16 + ln;
        bh8 kf0 = *(const bh8*)(&Kt[(n*8 + ( quad    ^ (ln&7)))*8]);
        bh8 kf1 = *(const bh8*)(&Kt[(n*8 + ((4+quad) ^ (ln&7)))*8]);
        fx4 zz = (fx4){0.f,0.f,0.f,0.f};
        zz = __builtin_amdgcn_mfma_f32_16x16x32_bf16(qf[rg][0], kf0, zz, 0,0,0);
        zz = __builtin_amdgcn_mfma_f32_16x16x32_bf16(qf[rg][1], kf1, zz, 0,0,0);
        sacc[t] = zz;
      }

      if (diag){
        #pragma unroll
        for (int t=0;t<8;t++){
          int kg = k0 + t*16 + ln;
          #pragma unroll
          for (int r=0;r<4;r++){
            int qg = q0w + rg*16 + quad*4 + r;
            sacc[t][r] = (kg <= qg) ? sacc[t][r] : -3e38f;
          }
        }
      }

      float rowmax[4] = {-3e38f,-3e38f,-3e38f,-3e38f};
      #pragma unroll
      for (int t=0;t<8;t++)
        #pragma unroll
        for (int r=0;r<4;r++) rowmax[r] = fmaxf(rowmax[r], sacc[t][r]);
      #pragma unroll
      for (int r=0;r<4;r++)
        #pragma unroll
        for (int off=1; off<16; off<<=1)
          rowmax[r] = fmaxf(rowmax[r], __shfl_xor(rowmax[r], off, 64));

      float alpha[4], rowsum[4];
      #pragma unroll
      for (int r=0;r<4;r++){
        float mn = fmaxf(m_i[rg][r], rowmax[r]);
        alpha[r] = fexp2(m_i[rg][r] - mn);
        m_i[rg][r] = mn;
        rowsum[r] = 0.f;
      }
      #pragma unroll
      for (int t=0;t<8;t++)
        #pragma unroll
        for (int r=0;r<4;r++){
          float p = fexp2(sacc[t][r] - m_i[rg][r]);
          sacc[t][r] = p;
          rowsum[r] += p;
        }
      #pragma unroll
      for (int r=0;r<4;r++){
        #pragma unroll
        for (int off=1; off<16; off<<=1)
          rowsum[r] += __shfl_xor(rowsum[r], off, 64);
        l_i[rg][r] = l_i[rg][r]*alpha[r] + rowsum[r];
      }
      #pragma unroll
      for (int vt=0;vt<4;vt++)
        #pragma unroll
        for (int r=0;r<4;r++)
          oacc[rg][vt][r] *= alpha[r];

      // P: C-layout -> A-layout, swizzled per-wave LDS (reused across rg)
      #pragma unroll
      for (int t=0;t<8;t++){
        int c = 2*t + (ln>>3), jj = ln & 7;
        #pragma unroll
        for (int r=0;r<4;r++){
          int m = quad*4 + r;
          Pw[(m*16 + (c ^ m))*8 + jj] = f2bf_fast(sacc[t][r]);
        }
      }
      asm volatile("s_waitcnt lgkmcnt(0)" ::: "memory");

      // PV: 128 keys in 4 chunks, vdim in 4 subtiles
      #pragma unroll
      for (int s3=0; s3<4; s3++){
        int c = s3*4 + quad;
        bh8 pf = *(const bh8*)(&Pw[(ln*16 + (c ^ ln))*8]);
        #pragma unroll
        for (int vt=0; vt<4; vt++){
          int vd = vt*16 + ln;
          bh8 vf = *(const bh8*)(&Vt[(vd*16 + (c ^ ln))*8]);
          oacc[rg][vt] = __builtin_amdgcn_mfma_f32_16x16x32_bf16(pf, vf, oacc[rg][vt], 0,0,0);
        }
      }
      asm volatile("s_waitcnt lgkmcnt(0)" ::: "memory");  // drain before Pw reuse
    }
  }

  // epilogue: O = acc / l
  #pragma unroll
  for (int rg=0; rg<2; rg++)
    #pragma unroll
    for (int r=0;r<4;r++){
      float linv = 1.0f / l_i[rg][r];
      #pragma unroll
      for (int vt=0; vt<4; vt++){
        float ov = oacc[rg][vt][r] * linv;
        O[(size_t)(b*S_ + q0w + rg*16 + quad*4 + r)*D_ + headoff + vt*16 + ln] = f2bf(ov);
      }
    }
}

extern "C" void kernel_launch(void* const* d_in, const int* in_sizes, int n_in,
                              void* d_out, int out_size, void* d_ws, size_t ws_size,
                              hipStream_t stream){
  const float* q  = (const float*)d_in[0];
  const float* k  = (const float*)d_in[1];
  const float* v  = (const float*)d_in[2];
  const float* Wq = (const float*)d_in[3];
  const float* Wk = (const float*)d_in[4];
  const float* Wv = (const float*)d_in[5];
  const float* Wo = (const float*)d_in[6];
  // d_in[7] = causal mask, statically known -> ignored

  u16* ws  = (u16*)d_ws;
  u16* WT  = ws;                                // 4 x 1M bf16 (Wq*C1, Wk, Wv, Wo)^T
  u16* xa  = WT + (size_t)4*1024*1024;          // q bf16, later v bf16
  u16* xb  = xa + MD_;                          // k bf16, later VtG
  u16* Qp  = xb + MD_;                          // Q proj (C1-scaled), later O
  u16* Kp  = Qp + MD_;                          // 4M + 4*MD = 75.5 MB total

  transpose4_k<<<dim3(32,32,4), dim3(32,8), 0, stream>>>(Wq, Wk, Wv, Wo, WT);

  const int n8 = (int)(MD_/8);
  cvt_k<<<dim3((n8+255)/256,1,2), 256, 0, stream>>>(q, k, xa, n8);      // xa=q, xb=k (bf16)

  gemm_bt<0><<<dim3(8,64,2), 256, 0, stream>>>(xa, WT, (void*)Qp);     // Qp, Kp

  cvt_k<<<dim3((n8+255)/256,1,1), 256, 0, stream>>>(v, v, xa, n8);      // xa=v (bf16)
  gemm_bt<2><<<dim3(8,64,1), 256, 0, stream>>>(xa, WT + (size_t)2*1024*1024, (void*)xb); // xb=VtG

  attn_k<<<dim3(S_/128, B_*H_), 256, 0, stream>>>(Qp, Kp, xb, Qp);      // O over Q

  gemm_bt<1><<<dim3(8,64,1), 256, 0, stream>>>(Qp, WT + (size_t)3*1024*1024, d_out);
}

// Round 6
// 473.362 us; speedup vs baseline: 1.2405x; 1.2405x over previous
//
#include <hip/hip_runtime.h>
#include <hip/hip_bf16.h>
#include <stdint.h>

#define B_  4
#define S_  2048
#define D_  1024
#define H_  16
#define DK_ 64
#define M_  (B_*S_)                 // 8192
#define MD_ ((size_t)M_*D_)         // 8388608

typedef unsigned short u16;
typedef unsigned int   u32;
using bh8 = __attribute__((ext_vector_type(8))) short;
using fx4 = __attribute__((ext_vector_type(4))) float;
using us4 = __attribute__((ext_vector_type(4))) unsigned short;

#define C1_ 0.18033688011112042f    // (1/sqrt(64)) * log2(e)

__device__ __forceinline__ u16 f2bf(float f){
  union { float f; u32 u; } v; v.f = f;
  u32 r = v.u + 0x7FFFu + ((v.u >> 16) & 1u);
  return (u16)(r >> 16);
}
__device__ __forceinline__ u16 f2bf_fast(float f){
  union { float f; u32 u; } v; v.f = f;
  return (u16)((v.u + 0x8000u) >> 16);
}
__device__ __forceinline__ float fexp2(float x){
  float r;
  asm("v_exp_f32 %0, %1\n\ts_nop 0" : "=v"(r) : "v"(x));
  return r;
}
// async global->LDS, 16B/lane; LDS dest = wave-uniform base + lane*16
__device__ __forceinline__ void gl16(const void* g, void* l){
  __builtin_amdgcn_global_load_lds(
      (const __attribute__((address_space(1))) unsigned int*)g,
      (__attribute__((address_space(3))) unsigned int*)l, 16, 0, 0);
}

// ---------- 4x transpose+convert; z==0 (Wq) pre-scaled by C1_ ----------
__global__ __launch_bounds__(256) void transpose4_k(const float* __restrict__ W0,
                                                    const float* __restrict__ W1,
                                                    const float* __restrict__ W2,
                                                    const float* __restrict__ W3,
                                                    u16* __restrict__ out){
  int z = blockIdx.z;
  const float* in = (z==0)? W0 : (z==1)? W1 : (z==2)? W2 : W3;
  float scale = (z==0)? C1_ : 1.0f;
  u16* o = out + (size_t)z*1024*1024;
  __shared__ u16 tile[32][33];
  int tx = threadIdx.x, ty = threadIdx.y;
  int x0 = blockIdx.x*32, y0 = blockIdx.y*32;
  #pragma unroll
  for (int j=0;j<32;j+=8) tile[ty+j][tx] = f2bf(in[(size_t)(y0+ty+j)*D_ + x0+tx]*scale);
  __syncthreads();
  #pragma unroll
  for (int j=0;j<32;j+=8) o[(size_t)(x0+ty+j)*D_ + y0+tx] = tile[tx][ty+j];
}

// ---------- fp32 -> bf16 convert; z selects src, dst offset z*MD ----------
__global__ __launch_bounds__(256) void cvt_k(const float* __restrict__ s0,
                                             const float* __restrict__ s1,
                                             u16* __restrict__ dst, int n8){
  int z = blockIdx.z;
  const float* in = z ? s1 : s0;
  u16* out = dst + (size_t)z*MD_;
  int i = blockIdx.x*256 + threadIdx.x;
  if (i >= n8) return;
  const float4* p = (const float4*)(in + (size_t)i*8);
  float4 a0 = p[0], a1 = p[1];
  u16 o[8];
  o[0]=f2bf(a0.x); o[1]=f2bf(a0.y); o[2]=f2bf(a0.z); o[3]=f2bf(a0.w);
  o[4]=f2bf(a1.x); o[5]=f2bf(a1.y); o[6]=f2bf(a1.z); o[7]=f2bf(a1.w);
  *(bh8*)(out + (size_t)i*8) = *(bh8*)o;
}

// ---------- C = A @ BT^T, K=N=1024, bf16 in, fp32 accum ----------
// MODE 0: bf16 C (z-batched). MODE 1: fp32 C. MODE 2: bf16 C stored as
// per-head V^T. BK=64 tiles (halved barrier count vs BK=32); frags re-read
// per 32-K substep to hold VGPR pressure.
template<int MODE>
__global__ __launch_bounds__(256) void gemm_bt(const u16* __restrict__ Abase,
                                               const u16* __restrict__ BTbase,
                                               void* __restrict__ Cbase){
  __shared__ __align__(16) u16 Asl[128*64];
  __shared__ __align__(16) u16 Bsl[128*64];
  int z = blockIdx.z;
  const u16* A  = Abase  + (size_t)z*MD_;
  const u16* BT = BTbase + (size_t)z*1024*1024;
  int tid  = threadIdx.x;
  int w    = tid >> 6, lane = tid & 63, quad = lane >> 4, ln = lane & 15;
  int waveM = w >> 1, waveN = w & 1;
  int rowBase = blockIdx.y*128, colBase = blockIdx.x*128;

  fx4 acc[4][4];
  #pragma unroll
  for (int i=0;i<4;i++)
    #pragma unroll
    for (int j=0;j<4;j++) acc[i][j] = (fx4){0.f,0.f,0.f,0.f};

  for (int k0 = 0; k0 < D_; k0 += 64){
    __syncthreads();
    #pragma unroll
    for (int i=0;i<4;i++){
      int slot = i*256 + tid;
      int kc = slot >> 7, r = slot & 127;
      gl16(&A [(size_t)(rowBase + r)*D_ + k0 + kc*8], &Asl[slot*8]);
      gl16(&BT[(size_t)(colBase + r)*D_ + k0 + kc*8], &Bsl[slot*8]);
    }
    __syncthreads();
    #pragma unroll
    for (int ks=0; ks<2; ks++){
      bh8 af[4], bf[4];
      #pragma unroll
      for (int t=0;t<4;t++){
        af[t] = *(const bh8*)(&Asl[((ks*4+quad)*128 + waveM*64 + t*16 + ln)*8]);
        bf[t] = *(const bh8*)(&Bsl[((ks*4+quad)*128 + waveN*64 + t*16 + ln)*8]);
      }
      #pragma unroll
      for (int i=0;i<4;i++)
        #pragma unroll
        for (int j=0;j<4;j++)
          acc[i][j] = __builtin_amdgcn_mfma_f32_16x16x32_bf16(af[i], bf[j], acc[i][j], 0, 0, 0);
    }
  }

  // epilogue: C/D layout col = lane&15, row = quad*4 + reg  [m89/m91-verified]
  #pragma unroll
  for (int i=0;i<4;i++){
    int row0 = rowBase + waveM*64 + i*16 + quad*4;
    #pragma unroll
    for (int j=0;j<4;j++){
      int col = colBase + waveN*64 + j*16 + ln;
      if (MODE == 2){
        int bb = row0 >> 11, tok = row0 & (S_-1);
        int hh = col >> 6,  vd  = col & 63;
        us4 pk;
        #pragma unroll
        for (int r=0;r<4;r++) pk[r] = f2bf(acc[i][j][r]);
        *(us4*)&((u16*)Cbase)[((size_t)((bb*16+hh)*64+vd))*S_ + tok] = pk;
      } else {
        #pragma unroll
        for (int r=0;r<4;r++){
          if (MODE == 1) ((float*)Cbase)[(size_t)(row0 + r)*D_ + col] = acc[i][j][r];
          else ((u16*)Cbase + (size_t)z*MD_)[(size_t)(row0 + r)*D_ + col] = f2bf(acc[i][j][r]);
        }
      }
    }
  }
}

// ---------- flash attention, causal ----------
// Block = 128 q-rows (4 waves x 2 row-groups); k-tile = 128; K/V double-
// buffered with prefetch: tile kt+1's global_load_lds issued before computing
// tile kt, ONE barrier per tile -> load latency hidden behind softmax compute.
// Grid (bh, qtile): XCD = bh%8 -> per-(b,h) K/V L2 locality; uniform-work
// dispatch waves, heavy (high qt) first. XOR-swizzled 16B chunk slots
// (R4-verified: 0 bank conflicts). O aliases Q (disjoint per block).
__global__ __launch_bounds__(256) void attn_k(const u16* __restrict__ Q,
                                              const u16* __restrict__ Kp,
                                              const u16* __restrict__ VtG,
                                              u16* __restrict__ O){
  __shared__ __align__(16) u16 Kt[2][128*64];   // 2 x 16 KB
  __shared__ __align__(16) u16 Vt[2][64*128];   // 2 x 16 KB
  __shared__ __align__(16) u16 Pb[4*16*128];    // 16 KB

  int bh = blockIdx.x; int b = bh>>4, h = bh&15;
  int qt = (int)gridDim.y - 1 - (int)blockIdx.y;   // heavy dispatch-waves first
  int tid = threadIdx.x;
  int w = tid >> 6, lane = tid & 63, quad = lane >> 4, ln = lane & 15;
  int q0w = qt*128 + w*32;
  size_t headoff = (size_t)h*DK_;

  bh8 qf[2][2];
  #pragma unroll
  for (int rg=0; rg<2; rg++){
    const u16* qp = Q + (size_t)(b*S_ + q0w + rg*16 + ln)*D_ + headoff + quad*8;
    qf[rg][0] = *(const bh8*)qp;
    qf[rg][1] = *(const bh8*)(qp + 32);
  }

  float m_i[2][4], l_i[2][4];
  fx4 oacc[2][4];
  #pragma unroll
  for (int rg=0; rg<2; rg++)
    #pragma unroll
    for (int r=0;r<4;r++){
      m_i[rg][r] = -3e38f; l_i[rg][r] = 0.f;
      oacc[rg][r] = (fx4){0.f,0.f,0.f,0.f};
    }

  auto stage = [&](int k0, int bi){
    #pragma unroll
    for (int i=0;i<4;i++){
      int s = i*256 + tid;
      int n = s >> 3, kc = (s & 7) ^ (n & 7);
      gl16(&Kp[(size_t)(b*S_ + k0 + n)*D_ + headoff + kc*8], &Kt[bi][s*8]);
    }
    #pragma unroll
    for (int i=0;i<4;i++){
      int s = i*256 + tid;
      int vd = s >> 4, c = (s & 15) ^ (vd & 15);
      gl16(&VtG[(size_t)(bh*64 + vd)*S_ + k0 + c*8], &Vt[bi][s*8]);
    }
  };

  u16* Pw = &Pb[w*16*128];
  int ntiles = qt + 1;

  stage(0, 0);
  __syncthreads();                       // drain prologue staging

  for (int kt=0; kt<ntiles; kt++){
    int cur = kt & 1;
    if (kt+1 < ntiles) stage((kt+1)*128, cur^1);   // prefetch, no wait
    const u16* Kc = Kt[cur];
    const u16* Vc = Vt[cur];
    int k0 = kt*128;
    bool diag = (kt == qt);

    #pragma unroll
    for (int rg=0; rg<2; rg++){
      // QK^T: 16q x 128k = 8 accs, 2 dk-steps
      fx4 sacc[8];
      #pragma unroll
      for (int t=0;t<8;t++){
        int n = t*16 + ln;
        bh8 kf0 = *(const bh8*)(&Kc[(n*8 + ( quad    ^ (ln&7)))*8]);
        bh8 kf1 = *(const bh8*)(&Kc[(n*8 + ((4+quad) ^ (ln&7)))*8]);
        fx4 zz = (fx4){0.f,0.f,0.f,0.f};
        zz = __builtin_amdgcn_mfma_f32_16x16x32_bf16(qf[rg][0], kf0, zz, 0,0,0);
        zz = __builtin_amdgcn_mfma_f32_16x16x32_bf16(qf[rg][1], kf1, zz, 0,0,0);
        sacc[t] = zz;
      }

      if (diag){
        #pragma unroll
        for (int t=0;t<8;t++){
          int kg = k0 + t*16 + ln;
          #pragma unroll
          for (int r=0;r<4;r++){
            int qg = q0w + rg*16 + quad*4 + r;
            sacc[t][r] = (kg <= qg) ? sacc[t][r] : -3e38f;
          }
        }
      }

      float rowmax[4] = {-3e38f,-3e38f,-3e38f,-3e38f};
      #pragma unroll
      for (int t=0;t<8;t++)
        #pragma unroll
        for (int r=0;r<4;r++) rowmax[r] = fmaxf(rowmax[r], sacc[t][r]);
      #pragma unroll
      for (int r=0;r<4;r++)
        #pragma unroll
        for (int off=1; off<16; off<<=1)
          rowmax[r] = fmaxf(rowmax[r], __shfl_xor(rowmax[r], off, 64));

      float alpha[4], rowsum[4];
      #pragma unroll
      for (int r=0;r<4;r++){
        float mn = fmaxf(m_i[rg][r], rowmax[r]);
        alpha[r] = fexp2(m_i[rg][r] - mn);
        m_i[rg][r] = mn;
        rowsum[r] = 0.f;
      }
      #pragma unroll
      for (int t=0;t<8;t++)
        #pragma unroll
        for (int r=0;r<4;r++){
          float p = fexp2(sacc[t][r] - m_i[rg][r]);
          sacc[t][r] = p;
          rowsum[r] += p;
        }
      #pragma unroll
      for (int r=0;r<4;r++){
        #pragma unroll
        for (int off=1; off<16; off<<=1)
          rowsum[r] += __shfl_xor(rowsum[r], off, 64);
        l_i[rg][r] = l_i[rg][r]*alpha[r] + rowsum[r];
      }
      #pragma unroll
      for (int vt=0;vt<4;vt++)
        #pragma unroll
        for (int r=0;r<4;r++)
          oacc[rg][vt][r] *= alpha[r];

      // P: C-layout -> A-layout via per-wave swizzled LDS (reused across rg)
      #pragma unroll
      for (int t=0;t<8;t++){
        int c = 2*t + (ln>>3), jj = ln & 7;
        #pragma unroll
        for (int r=0;r<4;r++){
          int m = quad*4 + r;
          Pw[(m*16 + (c ^ m))*8 + jj] = f2bf_fast(sacc[t][r]);
        }
      }
      asm volatile("s_waitcnt lgkmcnt(0)" ::: "memory");

      // PV: 128 keys in 4 chunks, vdim in 4 subtiles
      #pragma unroll
      for (int s3=0; s3<4; s3++){
        int c = s3*4 + quad;
        bh8 pf = *(const bh8*)(&Pw[(ln*16 + (c ^ ln))*8]);
        #pragma unroll
        for (int vt=0; vt<4; vt++){
          int vd = vt*16 + ln;
          bh8 vf = *(const bh8*)(&Vc[(vd*16 + (c ^ ln))*8]);
          oacc[rg][vt] = __builtin_amdgcn_mfma_f32_16x16x32_bf16(pf, vf, oacc[rg][vt], 0,0,0);
        }
      }
      asm volatile("s_waitcnt lgkmcnt(0)" ::: "memory");  // drain before Pw reuse
    }
    __syncthreads();   // prefetch arrived (vmcnt drain overlapped compute); buffers safe
  }

  // epilogue: O = acc / l
  #pragma unroll
  for (int rg=0; rg<2; rg++)
    #pragma unroll
    for (int r=0;r<4;r++){
      float linv = 1.0f / l_i[rg][r];
      #pragma unroll
      for (int vt=0; vt<4; vt++){
        float ov = oacc[rg][vt][r] * linv;
        O[(size_t)(b*S_ + q0w + rg*16 + quad*4 + r)*D_ + headoff + vt*16 + ln] = f2bf(ov);
      }
    }
}

extern "C" void kernel_launch(void* const* d_in, const int* in_sizes, int n_in,
                              void* d_out, int out_size, void* d_ws, size_t ws_size,
                              hipStream_t stream){
  const float* q  = (const float*)d_in[0];
  const float* k  = (const float*)d_in[1];
  const float* v  = (const float*)d_in[2];
  const float* Wq = (const float*)d_in[3];
  const float* Wk = (const float*)d_in[4];
  const float* Wv = (const float*)d_in[5];
  const float* Wo = (const float*)d_in[6];
  // d_in[7] = causal mask, statically known -> ignored

  u16* ws  = (u16*)d_ws;
  u16* WT  = ws;                                // 4 x 1M bf16 (Wq*C1, Wk, Wv, Wo)^T
  u16* xa  = WT + (size_t)4*1024*1024;          // q bf16, later v bf16
  u16* xb  = xa + MD_;                          // k bf16, later VtG
  u16* Qp  = xb + MD_;                          // Q proj (C1-scaled), later O
  u16* Kp  = Qp + MD_;                          // 4M + 4*MD = 75.5 MB total

  transpose4_k<<<dim3(32,32,4), dim3(32,8), 0, stream>>>(Wq, Wk, Wv, Wo, WT);

  const int n8 = (int)(MD_/8);
  cvt_k<<<dim3((n8+255)/256,1,2), 256, 0, stream>>>(q, k, xa, n8);      // xa=q, xb=k (bf16)

  gemm_bt<0><<<dim3(8,64,2), 256, 0, stream>>>(xa, WT, (void*)Qp);      // Qp, Kp

  cvt_k<<<dim3((n8+255)/256,1,1), 256, 0, stream>>>(v, v, xa, n8);      // xa=v (bf16)
  gemm_bt<2><<<dim3(8,64,1), 256, 0, stream>>>(xa, WT + (size_t)2*1024*1024, (void*)xb); // xb=VtG

  attn_k<<<dim3(B_*H_, S_/128), 256, 0, stream>>>(Qp, Kp, xb, Qp);      // O over Q

  gemm_bt<1><<<dim3(8,64,1), 256, 0, stream>>>(Qp, WT + (size_t)3*1024*1024, d_out);
}